// Round 7
// baseline (266.408 us; speedup 1.0000x reference)
//
#include <hip/hip_runtime.h>

#define N_GENOMES 4000
#define N_SAMPLES 2048
#define N_GENES   28000
#define N_SEQS    16000
#define MAXW      16                 // max genes per seq; P(exceed) ~1e-7
#define SLICE_F2  64                 // float2 per row-slice (128 samples)
#define ROW_F2    (N_SAMPLES / 2)    // 1024 float2 per full row
#define QCHUNK    128                // q's per block (32 per wave)
#define NCHUNK    (N_SEQS / QCHUNK)  // 125
#define PGRID     (8 * NCHUNK)       // 1000 blocks per phase (8 slices x 125 chunks)

typedef float v2f __attribute__((ext_vector_type(2)));

// ---------------- ELL build: seq -> up to MAXW (genome, pos) pairs ----------------

__global__ void ell_scatter_k(const int* __restrict__ seq_idx,
                              const int* __restrict__ genome_idx,
                              const float* __restrict__ pos,
                              int* __restrict__ counts,
                              int2* __restrict__ ell2) {
    int g = blockIdx.x * blockDim.x + threadIdx.x;
    if (g < N_GENES) {
        int q = seq_idx[g];
        int slot = atomicAdd(&counts[q], 1);
        if (slot < MAXW)
            ell2[q * MAXW + slot] = make_int2(genome_idx[g], __float_as_int(pos[g]));
    }
}

// ---------------- main: one 4MB sample-slice per XCD per LAUNCH ------------------
// out[q, s] = bias[q] * sum_{g : seq_idx[g]==q} A[gi,s] * 2^(1 - pos[g]*B[gi,s])
//
// Round-6 lesson: both "phases" of a single 2000-block launch are co-resident ->
// each XCD served TWO 4MB slices + write-back out traffic -> L2 thrash (FETCH
// only fell 215->157). Fixes: (1) hard phase separation via two launches, each
// 1000 blocks, slice = blockIdx%8 -> one slice per XCD; (2) NT stores so the
// 65MB/phase of out writes bypass L2 (wave store = 512B fully contiguous -> full
// sectors, no r1-style amplification); (3) dual-q interleave to double MLP and
// halve the per-q counts->meta->gather serial chain.

__global__ __launch_bounds__(256) void main_slice_k(
    const float* __restrict__ A, const float* __restrict__ B,
    const float* __restrict__ bias,
    const int* __restrict__ counts, const int2* __restrict__ ell2,
    float* __restrict__ out, int slice_base)
{
    const int b     = blockIdx.x;
    const int slice = (b & 7) + slice_base;    // b%8 -> XCD id (round-robin dispatch)
    const int chunk = b >> 3;                  // 0..124
    const int wave  = threadIdx.x >> 6;
    const int lane  = threadIdx.x & 63;
    const int off   = slice * SLICE_F2 + lane; // float2 index within a row

    const float2* __restrict__ A2 = (const float2*)A;
    const float2* __restrict__ B2 = (const float2*)B;

    const int q0 = chunk * QCHUNK + wave * 32; // 32 consecutive q's per wave

    // Rare tail (cnt > 4, ~3.4% of q's): metadata on demand.
    auto do_tail = [&](const int2* __restrict__ row, int cnt,
                       float& accx, float& accy) {
#pragma unroll 1
        for (int base = 4; base < cnt; base += 4) {
            int2 et[4];
#pragma unroll
            for (int j = 0; j < 4; ++j) et[j] = row[base + j];
#pragma unroll
            for (int j = 0; j < 4; ++j) {
                if (base + j < cnt) {
                    const float2 a = A2[(size_t)et[j].x * ROW_F2 + off];
                    const float2 bb = B2[(size_t)et[j].x * ROW_F2 + off];
                    const float p = __int_as_float(et[j].y);
                    accx += a.x * exp2f(1.0f - p * bb.x);
                    accy += a.y * exp2f(1.0f - p * bb.y);
                }
            }
        }
    };

    for (int i = 0; i < 32; i += 2) {
        const int qa = q0 + i, qb = qa + 1;

        int ca = counts[qa]; if (ca > MAXW) ca = MAXW;
        int cb = counts[qb]; if (cb > MAXW) cb = MAXW;
        const int2* __restrict__ rowa = ell2 + qa * MAXW;
        const int2* __restrict__ rowb = ell2 + qb * MAXW;

        // Unconditional metadata preload (slots >= cnt hold poison but are
        // never consumed as addresses).
        int2 ea[4], eb[4];
#pragma unroll
        for (int j = 0; j < 4; ++j) { ea[j] = rowa[j]; eb[j] = rowb[j]; }

        // Issue all 16 gathers (both q's) before any consumption.
        float2 ava[4], bva[4], avb[4], bvb[4];
#pragma unroll
        for (int j = 0; j < 4; ++j) {
            if (j < ca) {
                ava[j] = A2[(size_t)ea[j].x * ROW_F2 + off];
                bva[j] = B2[(size_t)ea[j].x * ROW_F2 + off];
            }
            if (j < cb) {
                avb[j] = A2[(size_t)eb[j].x * ROW_F2 + off];
                bvb[j] = B2[(size_t)eb[j].x * ROW_F2 + off];
            }
        }

        float axa = 0.f, aya = 0.f, axb = 0.f, ayb = 0.f;
#pragma unroll
        for (int j = 0; j < 4; ++j) {
            if (j < ca) {
                const float p = __int_as_float(ea[j].y);
                axa += ava[j].x * exp2f(1.0f - p * bva[j].x);
                aya += ava[j].y * exp2f(1.0f - p * bva[j].y);
            }
            if (j < cb) {
                const float p = __int_as_float(eb[j].y);
                axb += avb[j].x * exp2f(1.0f - p * bvb[j].x);
                ayb += avb[j].y * exp2f(1.0f - p * bvb[j].y);
            }
        }

        if (ca > 4) do_tail(rowa, ca, axa, aya);
        if (cb > 4) do_tail(rowb, cb, axb, ayb);

        // NT stores: keep the 65MB/phase out-stream from evicting the slice.
        // Wave footprint per instruction = 64 lanes x 8B contiguous = 512B.
        const float bqa = bias[qa], bqb = bias[qb];
        v2f oa = { axa * bqa, aya * bqa };
        v2f ob = { axb * bqb, ayb * bqb };
        __builtin_nontemporal_store(oa, (v2f*)out + (size_t)qa * ROW_F2 + off);
        __builtin_nontemporal_store(ob, (v2f*)out + (size_t)qb * ROW_F2 + off);
    }
}

// ---------------- launch ----------------

extern "C" void kernel_launch(void* const* d_in, const int* in_sizes, int n_in,
                              void* d_out, int out_size, void* d_ws, size_t ws_size,
                              hipStream_t stream) {
    const float* A          = (const float*)d_in[0];   // (4000, 2048)
    const float* B          = (const float*)d_in[1];   // (4000, 2048)
    const float* bias       = (const float*)d_in[2];   // (16000,)
    const float* pos        = (const float*)d_in[3];   // (28000,)
    const int*   genome_idx = (const int*)d_in[4];     // (28000,)
    const int*   seq_idx    = (const int*)d_in[5];     // (28000,)
    float*       out        = (float*)d_out;           // (16000, 2048)

    // ws layout: [counts: 16000 int][ell2: 16000*16 int2]
    int*  counts = (int*)d_ws;
    int2* ell2   = (int2*)((char*)d_ws + ((N_SEQS * sizeof(int) + 15) & ~15));

    hipMemsetAsync(counts, 0, N_SEQS * sizeof(int), stream);
    ell_scatter_k<<<(N_GENES + 255) / 256, 256, 0, stream>>>(seq_idx, genome_idx, pos,
                                                             counts, ell2);
    // Phase 0: samples 0..1023 (slices 0-7, one per XCD). Phase 1: 1024..2047.
    main_slice_k<<<PGRID, 256, 0, stream>>>(A, B, bias, counts, ell2, out, 0);
    main_slice_k<<<PGRID, 256, 0, stream>>>(A, B, bias, counts, ell2, out, 8);
}

// Round 8
// 230.736 us; speedup vs baseline: 1.1546x; 1.1546x over previous
//
#include <hip/hip_runtime.h>

#define N_GENOMES 4000
#define N_SAMPLES 2048
#define N_GENES   28000
#define N_SEQS    16000
#define MAXW      16                  // max genes per seq; P(exceed) ~1e-7
#define SLICE_F   128                 // samples per slice (16 slices total)
#define SLICE_F4  32                  // float4 per slice = 32 lanes x 16B = 512B
#define ROW_F4    (N_SAMPLES / 4)     // 512 float4 per row
#define QWAVE     32                  // q's per wave
#define QBLOCK    128                 // 4 waves x 32 q's
#define NCHUNK    (N_SEQS / QBLOCK)   // 125 (exact)
#define PGRID     (8 * NCHUNK)        // 1000 blocks per phase

typedef float v4f __attribute__((ext_vector_type(4)));

// ---------------- ELL build: seq -> up to MAXW (genome, pos) pairs ----------------

__global__ void ell_scatter_k(const int* __restrict__ seq_idx,
                              const int* __restrict__ genome_idx,
                              const float* __restrict__ pos,
                              int* __restrict__ counts,
                              int2* __restrict__ ell2) {
    int g = blockIdx.x * blockDim.x + threadIdx.x;
    if (g < N_GENES) {
        int q = seq_idx[g];
        int slot = atomicAdd(&counts[q], 1);
        if (slot < MAXW)
            ell2[q * MAXW + slot] = make_int2(genome_idx[g], __float_as_int(pos[g]));
    }
}

// ---------------- main: XCD-pinned slice + lane-parallel meta + half-wave q ------
// out[q, s] = bias[q] * sum_{g : seq_idx[g]==q} A[gi,s] * 2^(1 - pos[g]*B[gi,s])
//
// r6/r7 lessons: slicing improves locality (FETCH 215->157) but lost more to
// (a) the counts->ell2->gather serial chain re-run 16x per q (once per slice)
// and (b) 8B/lane accesses (4x the VMEM instructions per byte). Fixes:
//   - lane-parallel metadata: one wave loads cnt/bias/4 ELL slots for 32 q's in
//     6 instructions; per-q values come from __shfl (registers, no memory chain).
//   - half-wave per q: lanes 0-31 serve qa, 32-63 serve qb, float4 per lane ->
//     every gather instruction moves 2 x 512B contiguous segments (1KB, = r0).
//   - two q-pairs batched -> up to 16KB outstanding per wave.
//   - NT stores, 512B contiguous per half-wave (sector-complete: no r1-style
//     amplification), keep the out-stream from evicting the slice in L2.

__global__ __launch_bounds__(256) void main_slice_k(
    const float* __restrict__ A, const float* __restrict__ B,
    const float* __restrict__ bias,
    const int* __restrict__ counts, const int2* __restrict__ ell2,
    float* __restrict__ out, int slice_base)
{
    const int b     = blockIdx.x;
    const int slice = (b & 7) + slice_base;   // b%8 -> XCD (round-robin dispatch)
    const int chunk = b >> 3;                 // 0..124
    const int wave  = threadIdx.x >> 6;
    const int lane  = threadIdx.x & 63;
    const int half  = lane >> 5;              // 0: serves qa, 1: serves qb
    const int l32   = lane & 31;

    const int q0 = chunk * QBLOCK + wave * QWAVE;   // max 15968; q0+31 <= 15999

    // ---- lane-parallel metadata preload for this wave's 32 q's ----
    const int myq = q0 + l32;
    int mycnt = counts[myq]; if (mycnt > MAXW) mycnt = MAXW;
    int2 me[4];
#pragma unroll
    for (int j = 0; j < 4; ++j) me[j] = ell2[myq * MAXW + j];
    const float mybias = bias[myq];

    const float4* __restrict__ A4 = (const float4*)A;
    const float4* __restrict__ B4 = (const float4*)B;
    const int off = slice * SLICE_F4 + l32;   // float4 index within a row

    for (int i = 0; i < QWAVE; i += 4) {
        // pair 0: q0+i / q0+i+1; pair 1: q0+i+2 / q0+i+3 (per half-wave)
        const int sa = i + half, sb = i + 2 + half;
        const int qa = q0 + sa,  qb = q0 + sb;
        const int ca = __shfl(mycnt, sa), cb = __shfl(mycnt, sb);

        // per-q meta via register broadcast (no memory access)
        int gia[4], gib[4]; float pa_[4], pb_[4];
#pragma unroll
        for (int j = 0; j < 4; ++j) {
            gia[j] = __shfl(me[j].x, sa);
            pa_[j] = __shfl(__int_as_float(me[j].y), sa);
            gib[j] = __shfl(me[j].x, sb);
            pb_[j] = __shfl(__int_as_float(me[j].y), sb);
        }

        // ---- issue both pairs' gathers (<=16 x 1KB) before any consumption ----
        float4 ava[4], bva[4], avb[4], bvb[4];
#pragma unroll
        for (int j = 0; j < 4; ++j) {
            if (j < ca) {
                ava[j] = A4[(size_t)gia[j] * ROW_F4 + off];
                bva[j] = B4[(size_t)gia[j] * ROW_F4 + off];
            }
        }
#pragma unroll
        for (int j = 0; j < 4; ++j) {
            if (j < cb) {
                avb[j] = A4[(size_t)gib[j] * ROW_F4 + off];
                bvb[j] = B4[(size_t)gib[j] * ROW_F4 + off];
            }
        }

        float4 aa = make_float4(0.f, 0.f, 0.f, 0.f);
        float4 ab = make_float4(0.f, 0.f, 0.f, 0.f);
#pragma unroll
        for (int j = 0; j < 4; ++j) {
            if (j < ca) {
                const float p = pa_[j];
                aa.x += ava[j].x * exp2f(1.0f - p * bva[j].x);
                aa.y += ava[j].y * exp2f(1.0f - p * bva[j].y);
                aa.z += ava[j].z * exp2f(1.0f - p * bva[j].z);
                aa.w += ava[j].w * exp2f(1.0f - p * bva[j].w);
            }
        }
#pragma unroll
        for (int j = 0; j < 4; ++j) {
            if (j < cb) {
                const float p = pb_[j];
                ab.x += avb[j].x * exp2f(1.0f - p * bvb[j].x);
                ab.y += avb[j].y * exp2f(1.0f - p * bvb[j].y);
                ab.z += avb[j].z * exp2f(1.0f - p * bvb[j].z);
                ab.w += avb[j].w * exp2f(1.0f - p * bvb[j].w);
            }
        }

        // ---- rare tails (cnt > 4, ~3.4% of q's): meta on demand ----
        if (ca > 4) {
            for (int g = 4; g < ca; ++g) {
                const int2 e = ell2[qa * MAXW + g];
                const float4 a = A4[(size_t)e.x * ROW_F4 + off];
                const float4 v = B4[(size_t)e.x * ROW_F4 + off];
                const float p = __int_as_float(e.y);
                aa.x += a.x * exp2f(1.0f - p * v.x);
                aa.y += a.y * exp2f(1.0f - p * v.y);
                aa.z += a.z * exp2f(1.0f - p * v.z);
                aa.w += a.w * exp2f(1.0f - p * v.w);
            }
        }
        if (cb > 4) {
            for (int g = 4; g < cb; ++g) {
                const int2 e = ell2[qb * MAXW + g];
                const float4 a = A4[(size_t)e.x * ROW_F4 + off];
                const float4 v = B4[(size_t)e.x * ROW_F4 + off];
                const float p = __int_as_float(e.y);
                ab.x += a.x * exp2f(1.0f - p * v.x);
                ab.y += a.y * exp2f(1.0f - p * v.y);
                ab.z += a.z * exp2f(1.0f - p * v.z);
                ab.w += a.w * exp2f(1.0f - p * v.w);
            }
        }

        // ---- NT stores: half-wave = 512B contiguous, sector-complete ----
        const float bqa = __shfl(mybias, sa);
        const float bqb = __shfl(mybias, sb);
        v4f oa = { aa.x * bqa, aa.y * bqa, aa.z * bqa, aa.w * bqa };
        v4f ob = { ab.x * bqb, ab.y * bqb, ab.z * bqb, ab.w * bqb };
        __builtin_nontemporal_store(oa, (v4f*)(out + (size_t)qa * N_SAMPLES) + off);
        __builtin_nontemporal_store(ob, (v4f*)(out + (size_t)qb * N_SAMPLES) + off);
    }
}

// ---------------- launch ----------------

extern "C" void kernel_launch(void* const* d_in, const int* in_sizes, int n_in,
                              void* d_out, int out_size, void* d_ws, size_t ws_size,
                              hipStream_t stream) {
    const float* A          = (const float*)d_in[0];   // (4000, 2048)
    const float* B          = (const float*)d_in[1];   // (4000, 2048)
    const float* bias       = (const float*)d_in[2];   // (16000,)
    const float* pos        = (const float*)d_in[3];   // (28000,)
    const int*   genome_idx = (const int*)d_in[4];     // (28000,)
    const int*   seq_idx    = (const int*)d_in[5];     // (28000,)
    float*       out        = (float*)d_out;           // (16000, 2048)

    // ws layout: [counts: 16000 int][ell2: 16000*16 int2]
    int*  counts = (int*)d_ws;
    int2* ell2   = (int2*)((char*)d_ws + ((N_SEQS * sizeof(int) + 15) & ~15));

    hipMemsetAsync(counts, 0, N_SEQS * sizeof(int), stream);
    ell_scatter_k<<<(N_GENES + 255) / 256, 256, 0, stream>>>(seq_idx, genome_idx, pos,
                                                             counts, ell2);
    // Phase 0: samples 0..1023 (slices 0-7, one per XCD). Phase 1: 1024..2047.
    main_slice_k<<<PGRID, 256, 0, stream>>>(A, B, bias, counts, ell2, out, 0);
    main_slice_k<<<PGRID, 256, 0, stream>>>(A, B, bias, counts, ell2, out, 8);
}